// Round 9
// baseline (1752.715 us; speedup 1.0000x reference)
//
#include <hip/hip_runtime.h>

#define NL   8
#define DIM  2048
#define NH   8
#define NKV  2
#define HD   256
#define KVL  4096
#define FFI  8192
#define PLD  256
#define POS  2047
#define NCH  128
#define CP   16

typedef float vfloat4 __attribute__((ext_vector_type(4)));

__device__ __forceinline__ float dot4(float4 a, float4 b){
  return a.x*b.x + a.y*b.y + a.z*b.z + a.w*b.w;
}

__device__ __forceinline__ float4 ntld4(const float4* p){
  vfloat4 v = __builtin_nontemporal_load((const vfloat4*)p);
  float4 r; r.x=v.x; r.y=v.y; r.z=v.z; r.w=v.w; return r;
}
__device__ __forceinline__ void ntst4(float4* p, float4 v){
  vfloat4 t; t.x=v.x; t.y=v.y; t.z=v.z; t.w=v.w;
  __builtin_nontemporal_store(t, (vfloat4*)p);
}

__device__ __forceinline__ float waveAllSum(float v){
#pragma unroll
  for(int o=1;o<64;o<<=1) v += __shfl_xor(v,o,64);
  return v;
}

__device__ __forceinline__ float blockSum256(float v, float* red){
  int lane = threadIdx.x & 63, w = threadIdx.x >> 6;
  v = waveAllSum(v);
  __syncthreads();
  if(lane==0) red[w] = v;
  __syncthreads();
  return red[0]+red[1]+red[2]+red[3];
}

__device__ __forceinline__ float gelu_tanh(float v){
  return 0.5f*v*(1.0f + tanhf(0.7978845608028654f*(v + 0.044715f*v*v*v)));
}

__device__ __forceinline__ float4 normRope(const float* __restrict__ raw, int lane,
    const float* __restrict__ gain, const float* __restrict__ cosT,
    const float* __restrict__ sinT, bool doRope){
  float4 v4 = ((const float4*)raw)[lane];
  float ss = waveAllSum(dot4(v4,v4));
  float sc = rsqrtf(ss*(1.f/HD) + 1e-6f);
  float4 n;
  if(gain){
    float4 g4 = ((const float4*)gain)[lane];
    n.x=v4.x*sc*g4.x; n.y=v4.y*sc*g4.y; n.z=v4.z*sc*g4.z; n.w=v4.w*sc*g4.w;
  } else {
    n.x=v4.x*sc; n.y=v4.y*sc; n.z=v4.z*sc; n.w=v4.w*sc;
  }
  if(!doRope) return n;
  float4 np;
  np.x=__shfl_xor(n.x,32,64); np.y=__shfl_xor(n.y,32,64);
  np.z=__shfl_xor(n.z,32,64); np.w=__shfl_xor(n.w,32,64);
  float4 c4 = ((const float4*)cosT)[lane];
  float4 s4 = ((const float4*)sinT)[lane];
  float sg = (lane < 32) ? -1.f : 1.f;
  float4 o;
  o.x = n.x*c4.x + sg*np.x*s4.x;
  o.y = n.y*c4.y + sg*np.y*s4.y;
  o.z = n.z*c4.z + sg*np.z*s4.z;
  o.w = n.w*c4.w + sg*np.w*s4.w;
  return o;
}

// producer: all stores done (syncthreads drains vmem) -> release fence + count
__device__ __forceinline__ void prodSignal(unsigned* c){
  __syncthreads();
  if(threadIdx.x == 0){
    __builtin_amdgcn_fence(__ATOMIC_RELEASE, "agent");
    __hip_atomic_fetch_add(c, 1u, __ATOMIC_RELAXED, __HIP_MEMORY_SCOPE_AGENT);
  }
}
// consumer: spin till count==n, acquire fence, then whole block proceeds
__device__ __forceinline__ void consWait(unsigned* c, unsigned n){
  if(threadIdx.x == 0){
    while(__hip_atomic_load(c, __ATOMIC_RELAXED, __HIP_MEMORY_SCOPE_AGENT) < n)
      __builtin_amdgcn_s_sleep(2);
    __builtin_amdgcn_fence(__ATOMIC_ACQUIRE, "agent");
  }
  __syncthreads();
}

// ---- init: hRes = hidden; xs = rms(hidden)*g_in[0] ----
__global__ __launch_bounds__(256,4) void init_k(const float* __restrict__ hidden,
    const float* __restrict__ gin, float* __restrict__ hRes, float* __restrict__ xs){
  __shared__ float red[4];
  int tid = threadIdx.x;
  float v[8]; float ss = 0.f;
#pragma unroll
  for(int i=0;i<8;i++){ v[i] = hidden[tid + i*256]; ss += v[i]*v[i]; }
  ss = blockSum256(ss, red);
  float r = rsqrtf(ss*(1.f/DIM) + 1e-6f);
#pragma unroll
  for(int i=0;i<8;i++){ int idx = tid + i*256; hRes[idx] = v[i]; xs[idx] = v[i]*r*gin[idx]; }
}

// ==== AB: qkv -> attn -> comb -> wo -> postattn, + independent KV copy ====
__global__ __launch_bounds__(256,4) void ab_k(
    const float* __restrict__ Wq, const float* __restrict__ Wk,
    const float* __restrict__ Wv, const float* __restrict__ Wo,
    const float* __restrict__ Ki, const float* __restrict__ Vi,
    float* __restrict__ Kl, float* __restrict__ Vl,
    const float* __restrict__ gq, const float* __restrict__ gk,
    const float* __restrict__ cosT, const float* __restrict__ sinT,
    const float* __restrict__ xs, float* __restrict__ qkvb,
    float* __restrict__ pm, float* __restrict__ pl, float* __restrict__ po,
    float* __restrict__ ao, float* __restrict__ y,
    const float* __restrict__ hRes, const float* __restrict__ gpa,
    const float* __restrict__ gpf, float* __restrict__ hMid, float* __restrict__ xm,
    unsigned* cnt){
  __shared__ float sh[2048];
  __shared__ float red[4];
  float4* sh4 = (float4*)sh;
  int b = blockIdx.x, tid = threadIdx.x, lane = tid & 63, wv = tid >> 6;
  unsigned* c_qkv  = cnt;
  unsigned* c_attn = cnt + 16;
  unsigned* c_comb = cnt + 32;
  unsigned* c_wo   = cnt + 48;

  if(b < 384){ // ---------------- qkv: 8 rows/block ----------------
#pragma unroll
    for(int i=0;i<2;i++) sh4[tid + i*256] = ((const float4*)xs)[tid + i*256];
    __syncthreads();
#pragma unroll
    for(int rr=0;rr<2;rr++){
      int r = b*8 + wv*2 + rr;
      const float* W; int row;
      if(r < 2048){ W = Wq; row = r; }
      else if(r < 2560){ W = Wk; row = r - 2048; }
      else { W = Wv; row = r - 2560; }
      const float4* Wr = (const float4*)(W + (size_t)row*DIM);
      float4 w8[8];
#pragma unroll
      for(int i=0;i<8;i++) w8[i] = Wr[i*64+lane];
      float acc = 0.f;
#pragma unroll
      for(int i=0;i<8;i++) acc += dot4(w8[i], sh4[i*64+lane]);
      acc = waveAllSum(acc);
      if(lane==0) qkvb[r] = acc;
    }
    prodSignal(c_qkv);
  } else if(b < 641){ // ---------------- attn partials ----------------
    consWait(c_qkv, 384);
    int b2 = b - 384;
    if(b2 == 256){ // POS-row writer
      int kvv = wv >> 1, isV = wv & 1;
      const float* raw = qkvb + (isV ? 2560 : 2048) + kvv*HD;
      float4 o = normRope(raw, lane, isV ? nullptr : gk, cosT, sinT, !isV);
      float* dst = (isV ? Vl : Kl) + ((size_t)kvv*KVL + POS)*HD;
      ((float4*)dst)[lane] = o;
      prodSignal(c_attn);
      return;
    }
    int kv = b2 & 1, c = b2 >> 1;
    float* q_s  = sh;          // 4*256
    float* vf_s = sh + 1024;   // 256
    float* s_sB = sh + 1280;   // 4*16
    float* s_wB = sh + 1344;   // 4*16
    bool fresh = (c == NCH-1);
    { float4 o = normRope(qkvb + (kv*4 + wv)*HD, lane, gq, cosT, sinT, true);
      ((float4*)(q_s + wv*HD))[lane] = o; }
    float4 kf4 = {0,0,0,0};
    if(fresh){
      if(wv == 3) kf4 = normRope(qkvb + 2048 + kv*HD, lane, gk, cosT, sinT, true);
      if(wv == 1){
        float4 o = normRope(qkvb + 2560 + kv*HD, lane, nullptr, cosT, sinT, false);
        ((float4*)vf_s)[lane] = o;
      }
    }
    __syncthreads();
    float4 q4[4];
#pragma unroll
    for(int hh=0;hh<4;hh++) q4[hh] = ((const float4*)(q_s + hh*HD))[lane];
    const float4* Kp = (const float4*)(Ki + ((size_t)kv*KVL + c*CP)*HD);
#pragma unroll
    for(int j=0;j<4;j++){
      int p = wv*4 + j;
      float4 k4 = (fresh && p==CP-1) ? kf4 : Kp[(size_t)p*64 + lane];
      float d0 = dot4(k4,q4[0]), d1 = dot4(k4,q4[1]);
      float d2 = dot4(k4,q4[2]), d3 = dot4(k4,q4[3]);
      d0 = waveAllSum(d0); d1 = waveAllSum(d1);
      d2 = waveAllSum(d2); d3 = waveAllSum(d3);
      if(lane==0){ s_sB[0*CP+p]=d0; s_sB[1*CP+p]=d1; s_sB[2*CP+p]=d2; s_sB[3*CP+p]=d3; }
    }
    __syncthreads();
    if(tid < 64){
      int hh = tid >> 4, pp = tid & 15;
      float s = s_sB[hh*CP+pp];
      float m = s;
#pragma unroll
      for(int o=1;o<16;o<<=1) m = fmaxf(m, __shfl_xor(m,o,64));
      float e = __expf(s - m);
      float ls = e;
#pragma unroll
      for(int o=1;o<16;o<<=1) ls += __shfl_xor(ls,o,64);
      s_wB[hh*CP+pp] = e;
      if(pp==0){ int hg = kv*4 + hh; pm[hg*NCH + c] = m; pl[hg*NCH + c] = ls; }
    }
    __syncthreads();
    int d = tid;
    const float* Vp = Vi + ((size_t)kv*KVL + c*CP)*HD;
    float vv[CP];
#pragma unroll
    for(int p2=0;p2<CP;p2++) vv[p2] = Vp[(size_t)p2*HD + d];
    if(fresh) vv[CP-1] = vf_s[d];
    float acc[4] = {0.f,0.f,0.f,0.f};
#pragma unroll
    for(int p2=0;p2<CP;p2++){
#pragma unroll
      for(int hh=0;hh<4;hh++) acc[hh] += s_wB[hh*CP+p2]*vv[p2];
    }
#pragma unroll
    for(int hh=0;hh<4;hh++)
      po[((size_t)(kv*4+hh)*NCH + c)*HD + d] = acc[hh];
    prodSignal(c_attn);
  } else if(b < 649){ // ---------------- combine: 1 head/block ----------------
    consWait(c_attn, 257);
    int h = b - 641;
    float* sm = sh; float* sl = sh + 128; float* se = sh + 256;
    if(tid < NCH){ sm[tid] = pm[h*NCH+tid]; sl[tid] = pl[h*NCH+tid]; }
    __syncthreads();
    float M = -1e30f;
    for(int c=0;c<NCH;c++) M = fmaxf(M, sm[c]);
    if(tid < NCH) se[tid] = __expf(sm[tid]-M);
    __syncthreads();
    float Lh = 0.f;
    for(int c=0;c<NCH;c++) Lh += sl[c]*se[c];
    float a0=0.f,a1=0.f,a2=0.f,a3=0.f;
#pragma unroll 1
    for(int c=0;c<NCH;c+=4){
      a0 += po[((size_t)h*NCH + c  )*HD + tid]*se[c];
      a1 += po[((size_t)h*NCH + c+1)*HD + tid]*se[c+1];
      a2 += po[((size_t)h*NCH + c+2)*HD + tid]*se[c+2];
      a3 += po[((size_t)h*NCH + c+3)*HD + tid]*se[c+3];
    }
    ao[h*HD + tid] = (a0+a1+a2+a3) / Lh;
    prodSignal(c_comb);
  } else if(b < 777){ // ---------------- wo GEMV: 16 rows/block ----------------
    consWait(c_comb, 8);
    int b4 = b - 649;
#pragma unroll
    for(int i=0;i<2;i++) sh4[tid + i*256] = ((const float4*)ao)[tid + i*256];
    __syncthreads();
#pragma unroll
    for(int j=0;j<4;j++){
      int r = b4*16 + wv*4 + j;
      const float4* Wr = (const float4*)(Wo + (size_t)r*DIM);
      float4 w8[8];
#pragma unroll
      for(int i=0;i<8;i++) w8[i] = Wr[i*64+lane];
      float acc = 0.f;
#pragma unroll
      for(int i=0;i<8;i++) acc += dot4(w8[i], sh4[i*64+lane]);
      acc = waveAllSum(acc);
      if(lane==0) y[r] = acc;
    }
    prodSignal(c_wo);
  } else if(b == 777){ // ---------------- post-attn: hMid, xm ----------------
    consWait(c_wo, 128);
    float yv[8]; float ss1 = 0.f;
#pragma unroll
    for(int i=0;i<8;i++){ yv[i] = y[tid + i*256]; ss1 += yv[i]*yv[i]; }
    ss1 = blockSum256(ss1, red);
    float r1 = rsqrtf(ss1*(1.f/DIM) + 1e-6f);
    float hv[8]; float ss2 = 0.f;
#pragma unroll
    for(int i=0;i<8;i++){
      int idx = tid + i*256;
      hv[i] = hRes[idx] + yv[i]*r1*gpa[idx];
      ss2 += hv[i]*hv[i];
    }
    ss2 = blockSum256(ss2, red);
    float r2 = rsqrtf(ss2*(1.f/DIM) + 1e-6f);
#pragma unroll
    for(int i=0;i<8;i++){
      int idx = tid + i*256;
      hMid[idx] = hv[i];
      xm[idx] = hv[i]*r2*gpf[idx];
    }
  } else { // ---------------- KV copy (independent), skip POS rows ----------------
    int b5 = b - 778;
#pragma unroll 4
    for(int i=0;i<32;i++){
      int gr = b5*128 + wv*32 + i;
      int pos = gr & 4095;
      if(pos == POS) continue;
      const float4* s; float4* dpt;
      if(gr < 8192){ s = (const float4*)Ki + (size_t)gr*64; dpt = (float4*)Kl + (size_t)gr*64; }
      else { int g2 = gr - 8192; s = (const float4*)Vi + (size_t)g2*64; dpt = (float4*)Vl + (size_t)g2*64; }
      ntst4(dpt + lane, ntld4(s + lane));
    }
  }
}

// ==== CDE: gateup -> down -> plg -> plp -> xnext ====
__global__ __launch_bounds__(256,4) void cde_k(
    const float* __restrict__ Wg, const float* __restrict__ Wu,
    const float* __restrict__ Wd, const float* __restrict__ Wpg,
    const float* __restrict__ Wpp,
    const float* __restrict__ xm, float* __restrict__ t, float* __restrict__ mv,
    const float* __restrict__ hMid, const float* __restrict__ gff,
    const float* __restrict__ pls, float* __restrict__ hFF, float* __restrict__ gb,
    float* __restrict__ u,
    const float* __restrict__ gpl, const float* __restrict__ lsc,
    const float* __restrict__ ginN, float* __restrict__ hRes, float* __restrict__ xs,
    float* __restrict__ outv,
    unsigned* cnt){
  __shared__ float sh[8192];
  __shared__ float red[4];
  float4* sh4 = (float4*)sh;
  int b = blockIdx.x, tid = threadIdx.x, lane = tid & 63, wv = tid >> 6;
  unsigned* c_gu   = cnt + 64;
  unsigned* c_down = cnt + 80;
  unsigned* c_plg  = cnt + 96;
  unsigned* c_plp  = cnt + 112;

  if(b < 256){ // ---------------- gateup: 32 j/block ----------------
#pragma unroll
    for(int i=0;i<2;i++) sh4[tid + i*256] = ((const float4*)xm)[tid + i*256];
    __syncthreads();
#pragma unroll 1
    for(int jj=0;jj<8;jj++){
      int j = b*32 + wv*8 + jj;
      const float4* Gr = (const float4*)(Wg + (size_t)j*DIM);
      const float4* Ur = (const float4*)(Wu + (size_t)j*DIM);
      float4 g8[8], u8[8];
#pragma unroll
      for(int i=0;i<8;i++) g8[i] = Gr[i*64+lane];
#pragma unroll
      for(int i=0;i<8;i++) u8[i] = Ur[i*64+lane];
      float ag = 0.f, au = 0.f;
#pragma unroll
      for(int i=0;i<8;i++){
        float4 bv = sh4[i*64+lane];
        ag += dot4(g8[i], bv);
        au += dot4(u8[i], bv);
      }
      ag = waveAllSum(ag);
      au = waveAllSum(au);
      if(lane==0) t[j] = gelu_tanh(ag)*au;
    }
    prodSignal(c_gu);
  } else if(b < 768){ // ---------------- down: 4 rows/block ----------------
    consWait(c_gu, 256);
#pragma unroll
    for(int i=0;i<8;i++) sh4[tid + i*256] = ((const float4*)t)[tid + i*256];
    __syncthreads();
    int r = (b-256)*4 + wv;
    const float4* Wr = (const float4*)(Wd + (size_t)r*FFI);
    float acc = 0.f;
#pragma unroll 1
    for(int bb=0;bb<4;bb++){
      float4 w8[8];
#pragma unroll
      for(int i=0;i<8;i++) w8[i] = Wr[(bb*8+i)*64+lane];
#pragma unroll
      for(int i=0;i<8;i++) acc += dot4(w8[i], sh4[(bb*8+i)*64+lane]);
    }
    acc = waveAllSum(acc);
    if(lane==0) mv[r] = acc;
    prodSignal(c_down);
  } else if(b < 832){ // ---------------- plg (+post_ff prologue) ----------------
    consWait(c_down, 512);
    float mvv[8]; float ss1 = 0.f;
#pragma unroll
    for(int i=0;i<8;i++){ mvv[i] = mv[tid + i*256]; ss1 += mvv[i]*mvv[i]; }
    ss1 = blockSum256(ss1, red);
    float r1 = rsqrtf(ss1*(1.f/DIM) + 1e-6f);
#pragma unroll
    for(int i=0;i<8;i++){
      int idx = tid + i*256;
      float hc = hMid[idx] + mvv[i]*r1*gff[idx];
      sh[idx] = hc;
      if(b==768) hFF[idx] = hc;
    }
    __syncthreads();
    int r = (b-768)*4 + wv;
    const float4* Wr = (const float4*)(Wpg + (size_t)r*DIM);
    float4 w8[8];
#pragma unroll
    for(int i=0;i<8;i++) w8[i] = Wr[i*64+lane];
    float acc = 0.f;
#pragma unroll
    for(int i=0;i<8;i++) acc += dot4(w8[i], sh4[i*64+lane]);
    acc = waveAllSum(acc);
    if(lane==0) gb[r] = gelu_tanh(acc)*pls[r];
    prodSignal(c_plg);
  } else if(b < 960){ // ---------------- plp: 16 rows/block ----------------
    consWait(c_plg, 64);
    if(tid < 64) sh4[tid] = ((const float4*)gb)[tid];
    __syncthreads();
#pragma unroll
    for(int j=0;j<4;j++){
      int r = (b-832)*16 + wv*4 + j;
      const float4* Wr = (const float4*)(Wpp + (size_t)r*PLD);
      float acc = dot4(Wr[lane], sh4[lane]);
      acc = waveAllSum(acc);
      if(lane==0) u[r] = acc;
    }
    prodSignal(c_plp);
  } else { // ---------------- xnext: h3 (+x for next layer / out) ----------------
    consWait(c_plp, 128);
    float uv[8]; float ss1 = 0.f;
#pragma unroll
    for(int i=0;i<8;i++){ uv[i] = u[tid + i*256]; ss1 += uv[i]*uv[i]; }
    ss1 = blockSum256(ss1, red);
    float r1 = rsqrtf(ss1*(1.f/DIM) + 1e-6f);
    float ls = lsc[0];
    float h3[8];
#pragma unroll
    for(int i=0;i<8;i++){
      int idx = tid + i*256;
      h3[i] = (hFF[idx] + uv[i]*r1*gpl[idx])*ls;
    }
    if(outv){
#pragma unroll
      for(int i=0;i<8;i++) outv[tid + i*256] = h3[i];
    } else {
      float ss2 = 0.f;
#pragma unroll
      for(int i=0;i<8;i++) ss2 += h3[i]*h3[i];
      ss2 = blockSum256(ss2, red);
      float r2 = rsqrtf(ss2*(1.f/DIM) + 1e-6f);
#pragma unroll
      for(int i=0;i<8;i++){
        int idx = tid + i*256;
        hRes[idx] = h3[i];
        xs[idx] = h3[i]*r2*ginN[idx];
      }
    }
  }
}

extern "C" void kernel_launch(void* const* d_in, const int* in_sizes, int n_in,
                              void* d_out, int out_size, void* d_ws, size_t ws_size,
                              hipStream_t stream){
  const float* hidden   = (const float*)d_in[0];
  const float* plc      = (const float*)d_in[3];
  const float* cos_s    = (const float*)d_in[4];
  const float* sin_s    = (const float*)d_in[5];
  const float* cos_f    = (const float*)d_in[6];
  const float* sin_f    = (const float*)d_in[7];
  const float* K_in     = (const float*)d_in[8];
  const float* V_in     = (const float*)d_in[9];
  const float* w_q      = (const float*)d_in[10];
  const float* w_k      = (const float*)d_in[11];
  const float* w_v      = (const float*)d_in[12];
  const float* w_o      = (const float*)d_in[13];
  const float* g_in_ln  = (const float*)d_in[14];
  const float* g_q_norm = (const float*)d_in[15];
  const float* g_k_norm = (const float*)d_in[16];
  const float* g_pa_ln  = (const float*)d_in[17];
  const float* g_pf_ln  = (const float*)d_in[18];
  const float* g_ff_ln  = (const float*)d_in[19];
  const float* w_gate   = (const float*)d_in[20];
  const float* w_up     = (const float*)d_in[21];
  const float* w_down   = (const float*)d_in[22];
  const float* w_plg    = (const float*)d_in[23];
  const float* w_plp    = (const float*)d_in[24];
  const float* g_pl_ln  = (const float*)d_in[25];
  const float* l_scal   = (const float*)d_in[26];

  float* out  = (float*)d_out;
  float* outK = out + DIM;
  float* outV = outK + (size_t)NL*NKV*KVL*HD;

  unsigned* cnt = (unsigned*)d_ws;     // 8 layers x 8 counters x 64B = 4 KB

  float* fws  = (float*)d_ws + 1024;
  float* hRes = fws;
  float* hMid = fws + 2048;
  float* hFF  = fws + 4096;
  float* xs   = fws + 6144;
  float* xm   = fws + 8192;
  float* qkvb = fws + 10240;  // 3072
  float* y    = fws + 13312;  // 2048
  float* t    = fws + 15360;  // 8192
  float* mv   = fws + 23552;  // 2048
  float* gb   = fws + 25600;  // 256
  float* u    = fws + 25856;  // 2048
  float* pm   = fws + 27904;  // 1024
  float* pl   = fws + 28928;  // 1024
  float* ao   = fws + 29952;  // 2048
  float* po   = fws + 32000;  // 262144

  (void)hipMemsetAsync(d_ws, 0, 4096, stream);
  init_k<<<1,256,0,stream>>>(hidden, g_in_ln, hRes, xs);

  for(int l=0;l<NL;l++){
    const float* cosT = (l==4) ? cos_f : cos_s;
    const float* sinT = (l==4) ? sin_f : sin_s;
    float* Kl = outK + (size_t)l*NKV*KVL*HD;
    float* Vl = outV + (size_t)l*NKV*KVL*HD;
    const float* Ki = K_in + (size_t)l*NKV*KVL*HD;
    const float* Vi = V_in + (size_t)l*NKV*KVL*HD;
    unsigned* lc = cnt + l*128;   // 8 counters x 16 uints

    ab_k<<<906,256,0,stream>>>(
        w_q + (size_t)l*NH*HD*DIM, w_k + (size_t)l*NKV*HD*DIM,
        w_v + (size_t)l*NKV*HD*DIM, w_o + (size_t)l*DIM*NH*HD,
        Ki, Vi, Kl, Vl,
        g_q_norm + l*HD, g_k_norm + l*HD, cosT, sinT,
        xs, qkvb, pm, pl, po, ao, y,
        hRes, g_pa_ln + (size_t)l*DIM, g_pf_ln + (size_t)l*DIM, hMid, xm,
        lc);

    cde_k<<<961,256,0,stream>>>(
        w_gate + (size_t)l*FFI*DIM, w_up + (size_t)l*FFI*DIM,
        w_down + (size_t)l*DIM*FFI, w_plg + (size_t)l*PLD*DIM,
        w_plp + (size_t)l*DIM*PLD,
        xm, t, mv,
        hMid, g_ff_ln + (size_t)l*DIM, plc + l*PLD, hFF, gb, u,
        g_pl_ln + (size_t)l*DIM, l_scal + l,
        g_in_ln + (size_t)((l+1)%NL)*DIM, hRes, xs,
        (l==NL-1) ? out : nullptr,
        lc);
  }
}